// Round 3
// baseline (247.981 us; speedup 1.0000x reference)
//
#include <hip/hip_runtime.h>

// Problem constants
#define BB    32
#define NF    500
#define FRAME 160
#define OV    40
#define KK    16
#define NS    (NF * FRAME)     // 80000
#define FEAT  256

// gain_a = (6+6)/2 * ln10/20 ; gain_b = 0 ; shape_gain = 10^(-6/20)
__device__ const float GAIN_A     = 0.6907755278982137f;
__device__ const float GAIN_B     = 0.0f;
__device__ const float SHAPE_GAIN = 0.5011872336272722f;

// Kernel 1: build adaptive filters w[b][f][cout][cin][k]  (64 floats per (b,f))
// One block of 64 threads per (b,f). Lane t -> output row t = cout*32+cin*16+k.
__global__ __launch_bounds__(64) void wcalc_kernel(
    const float* __restrict__ feats,  // (B, NF, 256)
    const float* __restrict__ ckw,    // (64, 256)
    const float* __restrict__ ckb,    // (64,)
    const float* __restrict__ fgw,    // (2, 256)
    const float* __restrict__ fgb,    // (2,)
    float* __restrict__ wout)         // (B*NF, 64)
{
    int bf = blockIdx.x;          // b*NF + f
    int t  = threadIdx.x;         // 0..63

    __shared__ float feat[FEAT];
    const float4* frow = (const float4*)(feats + (size_t)bf * FEAT);
    ((float4*)feat)[t] = frow[t];
    __syncthreads();

    // ck[t] = dot(feat, ckw[t,:]) + ckb[t]
    const float4* wr4 = (const float4*)(ckw + (size_t)t * FEAT);
    const float4* f4  = (const float4*)feat;
    float a0 = 0.f, a1 = 0.f, a2 = 0.f, a3 = 0.f;
    #pragma unroll 8
    for (int j = 0; j < FEAT / 4; ++j) {
        float4 wv = wr4[j];
        float4 fv = f4[j];
        a0 = fmaf(fv.x, wv.x, a0);
        a1 = fmaf(fv.y, wv.y, a1);
        a2 = fmaf(fv.z, wv.z, a2);
        a3 = fmaf(fv.w, wv.w, a3);
    }
    float ck = (a0 + a1) + (a2 + a3) + ckb[t];

    // sum of squares over each 32-lane half (one half per cout)
    float ssq = ck * ck;
    #pragma unroll
    for (int m = 1; m <= 16; m <<= 1) ssq += __shfl_xor(ssq, m);
    float norm = 1e-6f + sqrtf(ssq);

    int k = t & 15;
    float val = SHAPE_GAIN * (ck / norm) + ((k == 7) ? (1.0f - SHAPE_GAIN) : 0.0f);

    // gain logit for this half's cout: parallel partial dot + xor-reduce
    int half = t >> 5;            // == cout for this lane
    int l    = t & 31;
    const float* gw = fgw + half * FEAT;
    float gp = 0.f;
    #pragma unroll
    for (int m = 0; m < 8; ++m) gp = fmaf(feat[l + m * 32], gw[l + m * 32], gp);
    #pragma unroll
    for (int m = 1; m <= 16; m <<= 1) gp += __shfl_xor(gp, m);
    float gl   = gp + fgb[half];
    float gain = expf(GAIN_A * tanhf(gl) + GAIN_B);

    wout[(size_t)bf * 64 + t] = val * gain;
}

// Kernel 2: direct time-domain conv + overlap-add. One thread per output sample.
// out[b][cout][s], s = f*160 + t:
//   y(f,t)      = sum_ci sum_k w[b,f,cout,ci,k] * x[b,ci,s-k]   (x zero for s-k<0)
//   t in [40,160): out = y(f,t)
//   t in [0,40):   out = owin[39-t]*y(f,t) + (f>0)*owin[t]*y(f-1,160+t)
// Both terms use the same x window x[s-15..s].
__global__ __launch_bounds__(256) void conv_kernel(
    const float* __restrict__ x,     // (B, 2, NS)
    const float* __restrict__ w,     // (B*NF, 64)
    const float* __restrict__ owin,  // (40,)
    float* __restrict__ out)         // (B, 2, NS)
{
    int idx = blockIdx.x * 256 + threadIdx.x;   // 0 .. B*2*NS-1
    int s   = idx % NS;
    int bc  = idx / NS;
    int b    = bc >> 1;
    int cout = bc & 1;
    int f = s / FRAME;
    int t = s - f * FRAME;

    const float* x0 = x + ((size_t)b * 2 + 0) * NS;
    const float* x1 = x + ((size_t)b * 2 + 1) * NS;

    float xv0[KK], xv1[KK];
    #pragma unroll
    for (int k = 0; k < KK; ++k) {
        int xi = s - k;
        bool ok = (xi >= 0);
        xv0[k] = ok ? x0[xi] : 0.f;
        xv1[k] = ok ? x1[xi] : 0.f;
    }

    const float4* wf4 = (const float4*)(w + ((size_t)(b * NF + f) * 64 + cout * 32));
    float acc = 0.f;
    #pragma unroll
    for (int q = 0; q < 4; ++q) {
        float4 w0 = wf4[q];       // cin0 taps 4q..4q+3
        float4 w1 = wf4[q + 4];   // cin1 taps 4q..4q+3
        acc = fmaf(w0.x, xv0[4 * q + 0], acc);
        acc = fmaf(w0.y, xv0[4 * q + 1], acc);
        acc = fmaf(w0.z, xv0[4 * q + 2], acc);
        acc = fmaf(w0.w, xv0[4 * q + 3], acc);
        acc = fmaf(w1.x, xv1[4 * q + 0], acc);
        acc = fmaf(w1.y, xv1[4 * q + 1], acc);
        acc = fmaf(w1.z, xv1[4 * q + 2], acc);
        acc = fmaf(w1.w, xv1[4 * q + 3], acc);
    }

    float res;
    if (t < OV) {
        float hv = owin[(OV - 1) - t] * acc;
        if (f > 0) {
            const float4* wp4 = wf4 - 16;   // previous frame, same cout
            float acc2 = 0.f;
            #pragma unroll
            for (int q = 0; q < 4; ++q) {
                float4 w0 = wp4[q];
                float4 w1 = wp4[q + 4];
                acc2 = fmaf(w0.x, xv0[4 * q + 0], acc2);
                acc2 = fmaf(w0.y, xv0[4 * q + 1], acc2);
                acc2 = fmaf(w0.z, xv0[4 * q + 2], acc2);
                acc2 = fmaf(w0.w, xv0[4 * q + 3], acc2);
                acc2 = fmaf(w1.x, xv1[4 * q + 0], acc2);
                acc2 = fmaf(w1.y, xv1[4 * q + 1], acc2);
                acc2 = fmaf(w1.z, xv1[4 * q + 2], acc2);
                acc2 = fmaf(w1.w, xv1[4 * q + 3], acc2);
            }
            hv = fmaf(owin[t], acc2, hv);
        }
        res = hv;
    } else {
        res = acc;
    }
    out[idx] = res;
}

extern "C" void kernel_launch(void* const* d_in, const int* in_sizes, int n_in,
                              void* d_out, int out_size, void* d_ws, size_t ws_size,
                              hipStream_t stream) {
    const float* x     = (const float*)d_in[0];
    const float* feats = (const float*)d_in[1];
    const float* ckw   = (const float*)d_in[2];
    const float* ckb   = (const float*)d_in[3];
    const float* fgw   = (const float*)d_in[4];
    const float* fgb   = (const float*)d_in[5];
    const float* owin  = (const float*)d_in[6];
    float* out  = (float*)d_out;
    float* wbuf = (float*)d_ws;   // needs B*NF*64*4 = 4.1 MB

    hipLaunchKernelGGL(wcalc_kernel, dim3(BB * NF), dim3(64), 0, stream,
                       feats, ckw, ckb, fgw, fgb, wbuf);

    const int nout = BB * 2 * NS;              // 5,120,000
    hipLaunchKernelGGL(conv_kernel, dim3(nout / 256), dim3(256), 0, stream,
                       x, wbuf, owin, out);
}

// Round 4
// 179.239 us; speedup vs baseline: 1.3835x; 1.3835x over previous
//
#include <hip/hip_runtime.h>

// Problem constants
#define BB    32
#define NF    500
#define FRAME 160
#define OV    40
#define KK    16
#define NS    (NF * FRAME)     // 80000
#define FEAT  256

// gain_a = (6+6)/2 * ln10/20 ; gain_b = 0 ; shape_gain = 10^(-6/20)
__device__ const float GAIN_A     = 0.6907755278982137f;
__device__ const float SHAPE_GAIN = 0.5011872336272722f;

// ---------------------------------------------------------------------------
// Kernel A: transpose feats (B, NF, FEAT) -> featT (B, FEAT, NF)
// 64x64 tiles through LDS, fully coalesced both sides.
// ---------------------------------------------------------------------------
__global__ __launch_bounds__(256) void transpose_kernel(
    const float* __restrict__ feats, float* __restrict__ featT)
{
    int b  = blockIdx.z;
    int f0 = blockIdx.x * 64;     // 8 tiles (last partial: 448..499)
    int k0 = blockIdx.y * 64;     // 4 tiles
    __shared__ float tile[64][65];
    int tid = threadIdx.x;

    int kl4 = tid & 15;           // float4 index along k
    int flr = tid >> 4;           // 0..15
    #pragma unroll
    for (int it = 0; it < 4; ++it) {
        int fl = flr + it * 16;   // 0..63
        int f  = f0 + fl;
        if (f < NF) {
            float4 v = *(const float4*)(feats + ((size_t)(b * NF + f)) * FEAT + k0 + kl4 * 4);
            tile[kl4 * 4 + 0][fl] = v.x;
            tile[kl4 * 4 + 1][fl] = v.y;
            tile[kl4 * 4 + 2][fl] = v.z;
            tile[kl4 * 4 + 3][fl] = v.w;
        }
    }
    __syncthreads();

    int fc  = tid & 15;           // float4 index along f
    int kr0 = tid >> 4;
    #pragma unroll
    for (int it = 0; it < 4; ++it) {
        int kr    = kr0 + it * 16;  // 0..63
        int fbase = f0 + fc * 4;
        size_t orow = ((size_t)(b * FEAT + k0 + kr)) * NF;
        if (fbase + 3 < NF) {
            float4 v;
            v.x = tile[kr][fc * 4 + 0];
            v.y = tile[kr][fc * 4 + 1];
            v.z = tile[kr][fc * 4 + 2];
            v.w = tile[kr][fc * 4 + 3];
            *(float4*)(featT + orow + fbase) = v;
        } else {
            #pragma unroll
            for (int c = 0; c < 4; ++c)
                if (fbase + c < NF) featT[orow + fbase + c] = tile[kr][fc * 4 + c];
        }
    }
}

// ---------------------------------------------------------------------------
// Kernel B: filter build, restructured.
// Grid (8 f-tiles, 32 b), block 256 = 4 waves. Lane l (0..63) = frame f0+l.
// Wave w computes output rows w*16..w*16+15 (+ its cout's gain dot).
// featT reads: coalesced b32. ckw reads: wave-uniform -> scalar s_loads.
// ---------------------------------------------------------------------------
__global__ __launch_bounds__(256) void wcalc2_kernel(
    const float* __restrict__ featT,  // (B, FEAT, NF)
    const float* __restrict__ ckw,    // (64, 256)
    const float* __restrict__ ckb,    // (64,)
    const float* __restrict__ fgw,    // (2, 256)
    const float* __restrict__ fgb,    // (2,)
    float* __restrict__ wout)         // (B*NF, 64)
{
    int tile = blockIdx.x;            // 0..7
    int b    = blockIdx.y;            // 0..31
    int f0   = tile * 64;
    int tid  = threadIdx.x;
    int w    = tid >> 6;              // wave id 0..3
    int l    = tid & 63;              // frame offset
    int f    = f0 + l;
    bool valid = (f < NF);
    int fc   = valid ? f : (NF - 1);  // clamped load index

    // force wave-uniform scalars onto the SGPR path
    int ubase = __builtin_amdgcn_readfirstlane(w * 16);   // output row base
    int ucout = __builtin_amdgcn_readfirstlane(w >> 1);   // cout of these rows

    const float* ft    = featT + ((size_t)b * FEAT) * NF;
    const float* gwrow = fgw + ucout * FEAT;

    float acc[16];
    #pragma unroll
    for (int r = 0; r < 16; ++r) acc[r] = 0.f;
    float g = 0.f;

    #pragma unroll 2
    for (int c = 0; c < 32; ++c) {
        float fr[8];
        #pragma unroll
        for (int i = 0; i < 8; ++i)
            fr[i] = ft[(size_t)(c * 8 + i) * NF + fc];
        #pragma unroll
        for (int r = 0; r < 16; ++r) {
            const float* wrow = ckw + (size_t)(ubase + r) * FEAT + c * 8;
            #pragma unroll
            for (int i = 0; i < 8; ++i)
                acc[r] = fmaf(fr[i], wrow[i], acc[r]);
        }
        #pragma unroll
        for (int i = 0; i < 8; ++i)
            g = fmaf(fr[i], gwrow[c * 8 + i], g);
    }

    #pragma unroll
    for (int r = 0; r < 16; ++r) acc[r] += ckb[ubase + r];
    g += fgb[ucout];

    // sum of squares across the 32 rows of this cout (2 waves)
    float ssq = 0.f;
    #pragma unroll
    for (int r = 0; r < 16; ++r) ssq = fmaf(acc[r], acc[r], ssq);

    __shared__ float lds_p[4][64];
    lds_p[w][l] = ssq;
    __syncthreads();
    float s4   = lds_p[ucout * 2][l] + lds_p[ucout * 2 + 1][l];
    float norm = 1e-6f + sqrtf(s4);

    float gain = expf(GAIN_A * tanhf(g));
    float sc   = gain * SHAPE_GAIN / norm;
    float idv  = gain * (1.0f - SHAPE_GAIN);

    float o[16];
    #pragma unroll
    for (int r = 0; r < 16; ++r)
        o[r] = acc[r] * sc + ((r == 7) ? idv : 0.0f);   // row&15==7 <=> r==7

    if (valid) {
        float* dst = wout + ((size_t)(b * NF + f) * 64 + ubase);
        #pragma unroll
        for (int q = 0; q < 4; ++q) {
            float4 v;
            v.x = o[q * 4 + 0]; v.y = o[q * 4 + 1];
            v.z = o[q * 4 + 2]; v.w = o[q * 4 + 3];
            *(float4*)(dst + q * 4) = v;
        }
    }
}

// ---------------------------------------------------------------------------
// Fallback filter build (original, ws-light) — used only if ws too small.
// ---------------------------------------------------------------------------
__global__ __launch_bounds__(64) void wcalc_kernel(
    const float* __restrict__ feats, const float* __restrict__ ckw,
    const float* __restrict__ ckb, const float* __restrict__ fgw,
    const float* __restrict__ fgb, float* __restrict__ wout)
{
    int bf = blockIdx.x;
    int t  = threadIdx.x;
    __shared__ float feat[FEAT];
    const float4* frow = (const float4*)(feats + (size_t)bf * FEAT);
    ((float4*)feat)[t] = frow[t];
    __syncthreads();

    const float4* wr4 = (const float4*)(ckw + (size_t)t * FEAT);
    const float4* f4  = (const float4*)feat;
    float a0 = 0.f, a1 = 0.f, a2 = 0.f, a3 = 0.f;
    #pragma unroll 8
    for (int j = 0; j < FEAT / 4; ++j) {
        float4 wv = wr4[j]; float4 fv = f4[j];
        a0 = fmaf(fv.x, wv.x, a0); a1 = fmaf(fv.y, wv.y, a1);
        a2 = fmaf(fv.z, wv.z, a2); a3 = fmaf(fv.w, wv.w, a3);
    }
    float ck = (a0 + a1) + (a2 + a3) + ckb[t];
    float ssq = ck * ck;
    #pragma unroll
    for (int m = 1; m <= 16; m <<= 1) ssq += __shfl_xor(ssq, m);
    float norm = 1e-6f + sqrtf(ssq);
    int k = t & 15;
    float val = SHAPE_GAIN * (ck / norm) + ((k == 7) ? (1.0f - SHAPE_GAIN) : 0.0f);
    int half = t >> 5, l = t & 31;
    const float* gw = fgw + half * FEAT;
    float gp = 0.f;
    #pragma unroll
    for (int m = 0; m < 8; ++m) gp = fmaf(feat[l + m * 32], gw[l + m * 32], gp);
    #pragma unroll
    for (int m = 1; m <= 16; m <<= 1) gp += __shfl_xor(gp, m);
    float gain = expf(GAIN_A * tanhf(gp + fgb[half]));
    wout[(size_t)bf * 64 + t] = val * gain;
}

// ---------------------------------------------------------------------------
// Kernel C: direct conv + overlap-add, 8 outputs per thread.
// s0 = 8-aligned => group never straddles a frame or the OV boundary (40%8==0).
// ---------------------------------------------------------------------------
__global__ __launch_bounds__(256) void conv8_kernel(
    const float* __restrict__ x,     // (B, 2, NS)
    const float* __restrict__ w,     // (B*NF, 64)
    const float* __restrict__ owin,  // (40,)
    float* __restrict__ out)         // (B, 2, NS)
{
    int gidx = blockIdx.x * 256 + threadIdx.x;   // 0 .. 640000-1
    int o0 = gidx * 8;
    int bc = o0 / NS;
    int s0 = o0 - bc * NS;
    int b = bc >> 1, cout = bc & 1;
    int f  = s0 / FRAME;
    int t0 = s0 - f * FRAME;

    const float* xb = x + (size_t)b * 2 * NS;

    // x windows: xr[ci][i] = x[ci][s0-16+i], i in [0,24); zeros left of 0
    float xr[2][24];
    #pragma unroll
    for (int ci = 0; ci < 2; ++ci) {
        const float* xc = xb + (size_t)ci * NS + s0 - 16;
        #pragma unroll
        for (int c = 0; c < 6; ++c) {
            if (s0 - 16 + c * 4 >= 0) {
                float4 v = *(const float4*)(xc + c * 4);
                xr[ci][c * 4 + 0] = v.x; xr[ci][c * 4 + 1] = v.y;
                xr[ci][c * 4 + 2] = v.z; xr[ci][c * 4 + 3] = v.w;
            } else {
                xr[ci][c * 4 + 0] = 0.f; xr[ci][c * 4 + 1] = 0.f;
                xr[ci][c * 4 + 2] = 0.f; xr[ci][c * 4 + 3] = 0.f;
            }
        }
    }

    const float* wf = w + ((size_t)(b * NF + f) * 64 + cout * 32);
    float wr[32];
    #pragma unroll
    for (int q = 0; q < 8; ++q) {
        float4 v = ((const float4*)wf)[q];
        wr[q * 4 + 0] = v.x; wr[q * 4 + 1] = v.y;
        wr[q * 4 + 2] = v.z; wr[q * 4 + 3] = v.w;
    }

    float acc[8];
    #pragma unroll
    for (int j = 0; j < 8; ++j) acc[j] = 0.f;
    #pragma unroll
    for (int ci = 0; ci < 2; ++ci)
        #pragma unroll
        for (int k = 0; k < KK; ++k) {
            float wk = wr[ci * 16 + k];
            #pragma unroll
            for (int j = 0; j < 8; ++j)
                acc[j] = fmaf(wk, xr[ci][16 + j - k], acc[j]);
        }

    if (t0 < OV) {
        float acc2[8];
        #pragma unroll
        for (int j = 0; j < 8; ++j) acc2[j] = 0.f;
        if (f > 0) {
            const float* wp = wf - 64;   // previous frame, same cout
            float wr2[32];
            #pragma unroll
            for (int q = 0; q < 8; ++q) {
                float4 v = ((const float4*)wp)[q];
                wr2[q * 4 + 0] = v.x; wr2[q * 4 + 1] = v.y;
                wr2[q * 4 + 2] = v.z; wr2[q * 4 + 3] = v.w;
            }
            #pragma unroll
            for (int ci = 0; ci < 2; ++ci)
                #pragma unroll
                for (int k = 0; k < KK; ++k) {
                    float wk = wr2[ci * 16 + k];
                    #pragma unroll
                    for (int j = 0; j < 8; ++j)
                        acc2[j] = fmaf(wk, xr[ci][16 + j - k], acc2[j]);
                }
        }
        #pragma unroll
        for (int j = 0; j < 8; ++j)
            acc[j] = owin[(OV - 1) - (t0 + j)] * acc[j] + owin[t0 + j] * acc2[j];
    }

    float* dst = out + o0;
    float4 v0, v1;
    v0.x = acc[0]; v0.y = acc[1]; v0.z = acc[2]; v0.w = acc[3];
    v1.x = acc[4]; v1.y = acc[5]; v1.z = acc[6]; v1.w = acc[7];
    *(float4*)(dst)     = v0;
    *(float4*)(dst + 4) = v1;
}

extern "C" void kernel_launch(void* const* d_in, const int* in_sizes, int n_in,
                              void* d_out, int out_size, void* d_ws, size_t ws_size,
                              hipStream_t stream) {
    const float* x     = (const float*)d_in[0];
    const float* feats = (const float*)d_in[1];
    const float* ckw   = (const float*)d_in[2];
    const float* ckb   = (const float*)d_in[3];
    const float* fgw   = (const float*)d_in[4];
    const float* fgb   = (const float*)d_in[5];
    const float* owin  = (const float*)d_in[6];
    float* out  = (float*)d_out;

    const size_t WBYTES  = (size_t)BB * NF * 64 * 4;        // 4,096,000
    const size_t FTBYTES = (size_t)BB * FEAT * NF * 4;      // 16,384,000
    float* wbuf  = (float*)d_ws;
    float* featT = (float*)((char*)d_ws + WBYTES);

    if (ws_size >= WBYTES + FTBYTES) {
        hipLaunchKernelGGL(transpose_kernel, dim3(8, 4, BB), dim3(256), 0, stream,
                           feats, featT);
        hipLaunchKernelGGL(wcalc2_kernel, dim3(8, BB), dim3(256), 0, stream,
                           featT, ckw, ckb, fgw, fgb, wbuf);
    } else {
        hipLaunchKernelGGL(wcalc_kernel, dim3(BB * NF), dim3(64), 0, stream,
                           feats, ckw, ckb, fgw, fgb, wbuf);
    }

    const int nthreads = BB * 2 * NS / 8;     // 640,000
    hipLaunchKernelGGL(conv8_kernel, dim3(nthreads / 256), dim3(256), 0, stream,
                       x, wbuf, owin, out);
}

// Round 5
// 123.520 us; speedup vs baseline: 2.0076x; 1.4511x over previous
//
#include <hip/hip_runtime.h>

// Problem constants
#define BB    32
#define NF    500
#define FRAME 160
#define OV    40
#define KK    16
#define NS    (NF * FRAME)     // 80000
#define FEAT  256

#define NBODY (BB * 2 * NF * 15)   // 480000 threads, t in [40,160)
#define NOV   (BB * 2 * NF * 5)    // 160000 threads, t in [0,40)

// gain_a = (6+6)/2 * ln10/20 ; shape_gain = 10^(-6/20)
__device__ const float GAIN_A     = 0.6907755278982137f;
__device__ const float SHAPE_GAIN = 0.5011872336272722f;

// ---------------------------------------------------------------------------
// wcalc3: fused filter build. Grid (8 f-tiles, 32 b), block 1024 = 16 waves.
// Lane l = frame f0+l; wave w owns output rows w*4 .. w*4+3.
// feats staged straight from (B,NF,256) layout into LDS in two 128-k chunks,
// transposed-with-XOR-swizzle so compute reads are conflict-free.
// ckw rows are wave-uniform -> scalar s_load path via readfirstlane.
// ---------------------------------------------------------------------------
__global__ __launch_bounds__(1024) void wcalc3_kernel(
    const float* __restrict__ feats,  // (B, NF, 256)
    const float* __restrict__ ckw,    // (64, 256)
    const float* __restrict__ ckb,    // (64,)
    const float* __restrict__ fgw,    // (2, 256)
    const float* __restrict__ fgb,    // (2,)
    float* __restrict__ wout)         // (B*NF, 64)
{
    int tile = blockIdx.x;            // 0..7
    int b    = blockIdx.y;            // 0..31
    int f0   = tile * 64;
    int tid  = threadIdx.x;
    int w    = tid >> 6;              // 0..15
    int l    = tid & 63;              // frame offset within tile

    __shared__ float sf[128 * 64];    // 32 KB: [k_local][fr ^ swz]
    __shared__ float sr[16][64];      // 4 KB : per-wave ssq partials

    int rbase = __builtin_amdgcn_readfirstlane(w * 4);  // output row base
    int cout  = rbase >> 5;
    const float* gwrow = fgw + cout * FEAT;

    float acc[4] = {0.f, 0.f, 0.f, 0.f};
    float g = 0.f;

    for (int h = 0; h < 2; ++h) {     // two 128-feat chunks
        __syncthreads();              // previous chunk's readers are done
        #pragma unroll
        for (int p = 0; p < 2; ++p) {
            int F  = p * 1024 + tid;  // 0..2047 float4 slots
            int fr = F >> 5;          // 0..63 frame row
            int c4 = F & 31;          // float4 col within 128-k chunk
            int f  = f0 + fr;
            float4 v = make_float4(0.f, 0.f, 0.f, 0.f);
            if (f < NF)
                v = *(const float4*)(feats + ((size_t)(b * NF + f)) * FEAT
                                     + h * 128 + c4 * 4);
            int sw = fr ^ (c4 & 31);  // swz mask = (k_local>>2)&31 = c4
            sf[(4 * c4 + 0) * 64 + sw] = v.x;
            sf[(4 * c4 + 1) * 64 + sw] = v.y;
            sf[(4 * c4 + 2) * 64 + sw] = v.z;
            sf[(4 * c4 + 3) * 64 + sw] = v.w;
        }
        __syncthreads();

        #pragma unroll 2
        for (int cl = 0; cl < 16; ++cl) {
            int k8  = cl * 8;                 // local k base
            int kg  = h * 128 + k8;           // global k base
            int slo = (2 * cl) & 31;
            int shi = (2 * cl + 1) & 31;
            float fr8[8];
            #pragma unroll
            for (int i = 0; i < 4; ++i) fr8[i]     = sf[(k8 + i) * 64 + (l ^ slo)];
            #pragma unroll
            for (int i = 0; i < 4; ++i) fr8[4 + i] = sf[(k8 + 4 + i) * 64 + (l ^ shi)];
            #pragma unroll
            for (int r = 0; r < 4; ++r) {
                const float* wr = ckw + (size_t)(rbase + r) * FEAT + kg;
                #pragma unroll
                for (int i = 0; i < 8; ++i) acc[r] = fmaf(fr8[i], wr[i], acc[r]);
            }
            #pragma unroll
            for (int i = 0; i < 8; ++i) g = fmaf(fr8[i], gwrow[kg + i], g);
        }
    }

    #pragma unroll
    for (int r = 0; r < 4; ++r) acc[r] += ckb[rbase + r];
    g += fgb[cout];

    // sum of squares across this cout's 32 rows (8 waves), per frame lane
    float ssq = 0.f;
    #pragma unroll
    for (int r = 0; r < 4; ++r) ssq = fmaf(acc[r], acc[r], ssq);
    sr[w][l] = ssq;
    __syncthreads();
    float tot = 0.f;
    #pragma unroll
    for (int j = 0; j < 8; ++j) tot += sr[cout * 8 + j][l];
    float norm = 1e-6f + sqrtf(tot);

    float gain = expf(GAIN_A * tanhf(g));
    float sc   = gain * SHAPE_GAIN / norm;
    float idv  = gain * (1.0f - SHAPE_GAIN);

    int f = f0 + l;
    if (f < NF) {
        float o[4];
        #pragma unroll
        for (int r = 0; r < 4; ++r)
            o[r] = acc[r] * sc + ((((rbase + r) & 15) == 7) ? idv : 0.f);
        float4 v;
        v.x = o[0]; v.y = o[1]; v.z = o[2]; v.w = o[3];
        *(float4*)(wout + ((size_t)(b * NF + f)) * 64 + rbase) = v;
    }
}

// ---------------------------------------------------------------------------
// conv: direct time-domain conv + overlap-add, 8 outputs/thread, REGION-SPLIT:
//   threads [0, NBODY): body samples t in [40,160) — single filter, no guards
//   threads [NBODY, NBODY+NOV): overlap t in [0,40) — two filters, blended
// Waves are region-uniform (no per-lane dual-path waste).
// ---------------------------------------------------------------------------
__global__ __launch_bounds__(256) void conv_kernel(
    const float* __restrict__ x,     // (B, 2, NS)
    const float* __restrict__ w,     // (B*NF, 64)
    const float* __restrict__ owin,  // (40,)
    float* __restrict__ out)         // (B, 2, NS)
{
    int flat = blockIdx.x * 256 + threadIdx.x;   // 0 .. 639999
    if (flat < NBODY) {
        int g    = flat % 15;
        int rest = flat / 15;
        int f    = rest % NF;
        int bc   = rest / NF;        // b*2 + cout
        int b = bc >> 1, cout = bc & 1;
        int s0 = f * FRAME + OV + g * 8;   // >= 40, window never underflows

        const float* xb = x + (size_t)b * 2 * NS;
        float xr[2][24];
        #pragma unroll
        for (int ci = 0; ci < 2; ++ci) {
            const float* xc = xb + (size_t)ci * NS + s0 - 16;
            #pragma unroll
            for (int c = 0; c < 6; ++c) {
                float4 v = *(const float4*)(xc + c * 4);
                xr[ci][c * 4 + 0] = v.x; xr[ci][c * 4 + 1] = v.y;
                xr[ci][c * 4 + 2] = v.z; xr[ci][c * 4 + 3] = v.w;
            }
        }
        const float4* wf = (const float4*)(w + ((size_t)(b * NF + f) * 64 + cout * 32));
        float wr[32];
        #pragma unroll
        for (int q = 0; q < 8; ++q) {
            float4 v = wf[q];
            wr[q * 4 + 0] = v.x; wr[q * 4 + 1] = v.y;
            wr[q * 4 + 2] = v.z; wr[q * 4 + 3] = v.w;
        }
        float acc[8];
        #pragma unroll
        for (int j = 0; j < 8; ++j) acc[j] = 0.f;
        #pragma unroll
        for (int ci = 0; ci < 2; ++ci)
            #pragma unroll
            for (int k = 0; k < KK; ++k) {
                float wk = wr[ci * 16 + k];
                #pragma unroll
                for (int j = 0; j < 8; ++j)
                    acc[j] = fmaf(wk, xr[ci][16 + j - k], acc[j]);
            }
        float* dst = out + (size_t)bc * NS + s0;
        float4 v0, v1;
        v0.x = acc[0]; v0.y = acc[1]; v0.z = acc[2]; v0.w = acc[3];
        v1.x = acc[4]; v1.y = acc[5]; v1.z = acc[6]; v1.w = acc[7];
        *(float4*)(dst)     = v0;
        *(float4*)(dst + 4) = v1;
    } else {
        int flat2 = flat - NBODY;
        int g    = flat2 % 5;
        int rest = flat2 / 5;
        int f    = rest % NF;
        int bc   = rest / NF;
        int b = bc >> 1, cout = bc & 1;
        int t0 = g * 8;
        int s0 = f * FRAME + t0;

        const float* xb = x + (size_t)b * 2 * NS;
        float xr[2][24];
        #pragma unroll
        for (int ci = 0; ci < 2; ++ci) {
            const float* xc = xb + (size_t)ci * NS + s0 - 16;
            #pragma unroll
            for (int c = 0; c < 6; ++c) {
                if (s0 - 16 + c * 4 >= 0) {
                    float4 v = *(const float4*)(xc + c * 4);
                    xr[ci][c * 4 + 0] = v.x; xr[ci][c * 4 + 1] = v.y;
                    xr[ci][c * 4 + 2] = v.z; xr[ci][c * 4 + 3] = v.w;
                } else {
                    xr[ci][c * 4 + 0] = 0.f; xr[ci][c * 4 + 1] = 0.f;
                    xr[ci][c * 4 + 2] = 0.f; xr[ci][c * 4 + 3] = 0.f;
                }
            }
        }

        const float* wfb = w + ((size_t)(b * NF + f) * 64 + cout * 32);
        float res[8];
        #pragma unroll
        for (int j = 0; j < 8; ++j) res[j] = 0.f;

        float wr[32];
        if (f > 0) {   // previous frame's filter first (reuses wr regs)
            const float4* wp = (const float4*)(wfb - 64);
            #pragma unroll
            for (int q = 0; q < 8; ++q) {
                float4 v = wp[q];
                wr[q * 4 + 0] = v.x; wr[q * 4 + 1] = v.y;
                wr[q * 4 + 2] = v.z; wr[q * 4 + 3] = v.w;
            }
            float acc[8];
            #pragma unroll
            for (int j = 0; j < 8; ++j) acc[j] = 0.f;
            #pragma unroll
            for (int ci = 0; ci < 2; ++ci)
                #pragma unroll
                for (int k = 0; k < KK; ++k) {
                    float wk = wr[ci * 16 + k];
                    #pragma unroll
                    for (int j = 0; j < 8; ++j)
                        acc[j] = fmaf(wk, xr[ci][16 + j - k], acc[j]);
                }
            #pragma unroll
            for (int j = 0; j < 8; ++j) res[j] = owin[t0 + j] * acc[j];
        }
        {
            const float4* wf = (const float4*)wfb;
            #pragma unroll
            for (int q = 0; q < 8; ++q) {
                float4 v = wf[q];
                wr[q * 4 + 0] = v.x; wr[q * 4 + 1] = v.y;
                wr[q * 4 + 2] = v.z; wr[q * 4 + 3] = v.w;
            }
            float acc[8];
            #pragma unroll
            for (int j = 0; j < 8; ++j) acc[j] = 0.f;
            #pragma unroll
            for (int ci = 0; ci < 2; ++ci)
                #pragma unroll
                for (int k = 0; k < KK; ++k) {
                    float wk = wr[ci * 16 + k];
                    #pragma unroll
                    for (int j = 0; j < 8; ++j)
                        acc[j] = fmaf(wk, xr[ci][16 + j - k], acc[j]);
                }
            #pragma unroll
            for (int j = 0; j < 8; ++j)
                res[j] = fmaf(owin[(OV - 1) - (t0 + j)], acc[j], res[j]);
        }
        float* dst = out + (size_t)bc * NS + s0;
        float4 v0, v1;
        v0.x = res[0]; v0.y = res[1]; v0.z = res[2]; v0.w = res[3];
        v1.x = res[4]; v1.y = res[5]; v1.z = res[6]; v1.w = res[7];
        *(float4*)(dst)     = v0;
        *(float4*)(dst + 4) = v1;
    }
}

extern "C" void kernel_launch(void* const* d_in, const int* in_sizes, int n_in,
                              void* d_out, int out_size, void* d_ws, size_t ws_size,
                              hipStream_t stream) {
    const float* x     = (const float*)d_in[0];
    const float* feats = (const float*)d_in[1];
    const float* ckw   = (const float*)d_in[2];
    const float* ckb   = (const float*)d_in[3];
    const float* fgw   = (const float*)d_in[4];
    const float* fgb   = (const float*)d_in[5];
    const float* owin  = (const float*)d_in[6];
    float* out  = (float*)d_out;
    float* wbuf = (float*)d_ws;                 // B*NF*64*4 = 4.1 MB

    hipLaunchKernelGGL(wcalc3_kernel, dim3(8, BB), dim3(1024), 0, stream,
                       feats, ckw, ckb, fgw, fgb, wbuf);

    hipLaunchKernelGGL(conv_kernel, dim3((NBODY + NOV) / 256), dim3(256), 0, stream,
                       x, wbuf, owin, out);
}

// Round 7
// 119.186 us; speedup vs baseline: 2.0806x; 1.0364x over previous
//
#include <hip/hip_runtime.h>

// Problem constants
#define BB    32
#define NF    500
#define FRAME 160
#define OV    40
#define KK    16
#define NS    (NF * FRAME)     // 80000
#define FEAT  256

#define NBODY2 (BB * NF * 15)   // 240000 threads: t in [40,160), both couts
#define NOV2   (BB * NF * 5)    //  80000 threads: t in [0,40),   both couts

// gain_a = (6+6)/2 * ln10/20 ; shape_gain = 10^(-6/20)
__device__ const float GAIN_A     = 0.6907755278982137f;
__device__ const float SHAPE_GAIN = 0.5011872336272722f;

// ---------------------------------------------------------------------------
// wcalc4: filter build. Grid (8 f-tiles, 32 b, 2 cout-blocks), block 512 =
// 8 waves. Lane l = frame f0+l; wave w owns rows z*32 + w*4 .. +3 (wave-
// uniform -> ckw on the scalar path). feats staged to LDS transposed with
// XOR swizzle (conflict-free both sides). 512 blocks -> 2 blocks/CU so
// staging of one block overlaps compute of the other.
// ---------------------------------------------------------------------------
__global__ __launch_bounds__(512) void wcalc4_kernel(
    const float* __restrict__ feats,  // (B, NF, 256)
    const float* __restrict__ ckw,    // (64, 256)
    const float* __restrict__ ckb,    // (64,)
    const float* __restrict__ fgw,    // (2, 256)
    const float* __restrict__ fgb,    // (2,)
    float* __restrict__ wout)         // (B*NF, 64)
{
    int tile = blockIdx.x;            // 0..7
    int b    = blockIdx.y;            // 0..31
    int z    = blockIdx.z;            // cout block 0/1
    int f0   = tile * 64;
    int tid  = threadIdx.x;
    int w    = tid >> 6;              // 0..7
    int l    = tid & 63;              // frame offset within tile

    __shared__ float sf[128 * 64];    // 32 KB: [k_local][fr ^ swz]
    __shared__ float sr[8][64];       // 2 KB : per-wave ssq partials

    int rbase = __builtin_amdgcn_readfirstlane(z * 32 + w * 4);
    const float* gwrow = fgw + z * FEAT;

    float acc[4] = {0.f, 0.f, 0.f, 0.f};
    float g = 0.f;

    for (int h = 0; h < 2; ++h) {     // two 128-feat chunks
        __syncthreads();              // previous chunk's readers are done
        #pragma unroll
        for (int p = 0; p < 4; ++p) {
            int F  = p * 512 + tid;   // 0..2047 float4 slots
            int fr = F >> 5;          // 0..63 frame row
            int c4 = F & 31;          // float4 col within 128-k chunk
            int f  = f0 + fr;
            float4 v = make_float4(0.f, 0.f, 0.f, 0.f);
            if (f < NF)
                v = *(const float4*)(feats + ((size_t)(b * NF + f)) * FEAT
                                     + h * 128 + c4 * 4);
            int sw = fr ^ c4;         // swizzle
            sf[(4 * c4 + 0) * 64 + sw] = v.x;
            sf[(4 * c4 + 1) * 64 + sw] = v.y;
            sf[(4 * c4 + 2) * 64 + sw] = v.z;
            sf[(4 * c4 + 3) * 64 + sw] = v.w;
        }
        __syncthreads();

        #pragma unroll 2
        for (int cl = 0; cl < 16; ++cl) {
            int k8  = cl * 8;                 // local k base
            int kg  = h * 128 + k8;           // global k base
            int slo = (2 * cl) & 31;
            int shi = (2 * cl + 1) & 31;
            float fr8[8];
            #pragma unroll
            for (int i = 0; i < 4; ++i) fr8[i]     = sf[(k8 + i) * 64 + (l ^ slo)];
            #pragma unroll
            for (int i = 0; i < 4; ++i) fr8[4 + i] = sf[(k8 + 4 + i) * 64 + (l ^ shi)];
            #pragma unroll
            for (int r = 0; r < 4; ++r) {
                const float* wr = ckw + (size_t)(rbase + r) * FEAT + kg;
                #pragma unroll
                for (int i = 0; i < 8; ++i) acc[r] = fmaf(fr8[i], wr[i], acc[r]);
            }
            #pragma unroll
            for (int i = 0; i < 8; ++i) g = fmaf(fr8[i], gwrow[kg + i], g);
        }
    }

    #pragma unroll
    for (int r = 0; r < 4; ++r) acc[r] += ckb[rbase + r];
    g += fgb[z];

    // sum of squares across this cout's 32 rows (all 8 waves), per frame lane
    float ssq = 0.f;
    #pragma unroll
    for (int r = 0; r < 4; ++r) ssq = fmaf(acc[r], acc[r], ssq);
    sr[w][l] = ssq;
    __syncthreads();
    float tot = 0.f;
    #pragma unroll
    for (int j = 0; j < 8; ++j) tot += sr[j][l];
    float norm = 1e-6f + sqrtf(tot);

    float gain = expf(GAIN_A * tanhf(g));
    float sc   = gain * SHAPE_GAIN / norm;
    float idv  = gain * (1.0f - SHAPE_GAIN);

    int f = f0 + l;
    if (f < NF) {
        float o[4];
        #pragma unroll
        for (int r = 0; r < 4; ++r)
            o[r] = acc[r] * sc + ((((rbase + r) & 15) == 7) ? idv : 0.f);
        float4 v;
        v.x = o[0]; v.y = o[1]; v.z = o[2]; v.w = o[3];
        *(float4*)(wout + ((size_t)(b * NF + f)) * 64 + rbase) = v;
    }
}

// ---------------------------------------------------------------------------
// conv: direct conv + overlap-add. Each thread: 8 samples x BOTH couts
// (x window loaded once, couts sequential reusing wr/acc registers).
// Region split: [0, NBODY2) body t in [40,160); [NBODY2, +NOV2) overlap.
// ---------------------------------------------------------------------------
__global__ __launch_bounds__(256) void conv2_kernel(
    const float* __restrict__ x,     // (B, 2, NS)
    const float* __restrict__ w,     // (B*NF, 64)
    const float* __restrict__ owin,  // (40,)
    float* __restrict__ out)         // (B, 2, NS)
{
    int flat = blockIdx.x * 256 + threadIdx.x;   // 0 .. 319999
    if (flat < NBODY2) {
        int g    = flat % 15;
        int rest = flat / 15;
        int f    = rest % NF;
        int b    = rest / NF;
        int s0   = f * FRAME + OV + g * 8;       // >= 40: no underflow

        const float* xb = x + (size_t)b * 2 * NS;
        float xr[2][24];
        #pragma unroll
        for (int ci = 0; ci < 2; ++ci) {
            const float* xc = xb + (size_t)ci * NS + s0 - 16;
            #pragma unroll
            for (int c = 0; c < 6; ++c) {
                float4 v = *(const float4*)(xc + c * 4);
                xr[ci][c * 4 + 0] = v.x; xr[ci][c * 4 + 1] = v.y;
                xr[ci][c * 4 + 2] = v.z; xr[ci][c * 4 + 3] = v.w;
            }
        }
        const float* wfb = w + (size_t)(b * NF + f) * 64;
        #pragma unroll
        for (int cout = 0; cout < 2; ++cout) {
            const float4* wf = (const float4*)(wfb + cout * 32);
            float wr[32];
            #pragma unroll
            for (int q = 0; q < 8; ++q) {
                float4 v = wf[q];
                wr[q * 4 + 0] = v.x; wr[q * 4 + 1] = v.y;
                wr[q * 4 + 2] = v.z; wr[q * 4 + 3] = v.w;
            }
            float acc[8];
            #pragma unroll
            for (int j = 0; j < 8; ++j) acc[j] = 0.f;
            #pragma unroll
            for (int ci = 0; ci < 2; ++ci)
                #pragma unroll
                for (int k = 0; k < KK; ++k) {
                    float wk = wr[ci * 16 + k];
                    #pragma unroll
                    for (int j = 0; j < 8; ++j)
                        acc[j] = fmaf(wk, xr[ci][16 + j - k], acc[j]);
                }
            float* dst = out + (size_t)(b * 2 + cout) * NS + s0;
            float4 v0, v1;
            v0.x = acc[0]; v0.y = acc[1]; v0.z = acc[2]; v0.w = acc[3];
            v1.x = acc[4]; v1.y = acc[5]; v1.z = acc[6]; v1.w = acc[7];
            *(float4*)(dst)     = v0;
            *(float4*)(dst + 4) = v1;
        }
    } else {
        int flat2 = flat - NBODY2;
        int g    = flat2 % 5;
        int rest = flat2 / 5;
        int f    = rest % NF;
        int b    = rest / NF;
        int t0   = g * 8;
        int s0   = f * FRAME + t0;

        const float* xb = x + (size_t)b * 2 * NS;
        float xr[2][24];
        #pragma unroll
        for (int ci = 0; ci < 2; ++ci) {
            const float* xc = xb + (size_t)ci * NS + s0 - 16;
            #pragma unroll
            for (int c = 0; c < 6; ++c) {
                if (s0 - 16 + c * 4 >= 0) {
                    float4 v = *(const float4*)(xc + c * 4);
                    xr[ci][c * 4 + 0] = v.x; xr[ci][c * 4 + 1] = v.y;
                    xr[ci][c * 4 + 2] = v.z; xr[ci][c * 4 + 3] = v.w;
                } else {
                    xr[ci][c * 4 + 0] = 0.f; xr[ci][c * 4 + 1] = 0.f;
                    xr[ci][c * 4 + 2] = 0.f; xr[ci][c * 4 + 3] = 0.f;
                }
            }
        }

        // owin windows: o_tail[j] = owin[t0+j] (win2 for prev-frame tail),
        //               o_head[j] = owin[39-t0-j] (win1 for this frame head)
        float o_tail[8], o_head[8];
        {
            float4 a = *(const float4*)(owin + t0);
            float4 c = *(const float4*)(owin + t0 + 4);
            o_tail[0] = a.x; o_tail[1] = a.y; o_tail[2] = a.z; o_tail[3] = a.w;
            o_tail[4] = c.x; o_tail[5] = c.y; o_tail[6] = c.z; o_tail[7] = c.w;
            float4 d = *(const float4*)(owin + (32 - t0));
            float4 e = *(const float4*)(owin + (36 - t0));
            // owin[39-t0-j]: j=0 -> 39-t0 = (36-t0)+3
            o_head[0] = e.w; o_head[1] = e.z; o_head[2] = e.y; o_head[3] = e.x;
            o_head[4] = d.w; o_head[5] = d.z; o_head[6] = d.y; o_head[7] = d.x;
        }

        const float* wfb = w + (size_t)(b * NF + f) * 64;
        #pragma unroll
        for (int cout = 0; cout < 2; ++cout) {
            float res[8];
            #pragma unroll
            for (int j = 0; j < 8; ++j) res[j] = 0.f;

            float wr[32];
            if (f > 0) {   // previous frame's filter (tail contribution)
                const float4* wp = (const float4*)(wfb - 64 + cout * 32);
                #pragma unroll
                for (int q = 0; q < 8; ++q) {
                    float4 v = wp[q];
                    wr[q * 4 + 0] = v.x; wr[q * 4 + 1] = v.y;
                    wr[q * 4 + 2] = v.z; wr[q * 4 + 3] = v.w;
                }
                float acc[8];
                #pragma unroll
                for (int j = 0; j < 8; ++j) acc[j] = 0.f;
                #pragma unroll
                for (int ci = 0; ci < 2; ++ci)
                    #pragma unroll
                    for (int k = 0; k < KK; ++k) {
                        float wk = wr[ci * 16 + k];
                        #pragma unroll
                        for (int j = 0; j < 8; ++j)
                            acc[j] = fmaf(wk, xr[ci][16 + j - k], acc[j]);
                    }
                #pragma unroll
                for (int j = 0; j < 8; ++j) res[j] = o_tail[j] * acc[j];
            }
            {
                const float4* wf = (const float4*)(wfb + cout * 32);
                #pragma unroll
                for (int q = 0; q < 8; ++q) {
                    float4 v = wf[q];
                    wr[q * 4 + 0] = v.x; wr[q * 4 + 1] = v.y;
                    wr[q * 4 + 2] = v.z; wr[q * 4 + 3] = v.w;
                }
                float acc[8];
                #pragma unroll
                for (int j = 0; j < 8; ++j) acc[j] = 0.f;
                #pragma unroll
                for (int ci = 0; ci < 2; ++ci)
                    #pragma unroll
                    for (int k = 0; k < KK; ++k) {
                        float wk = wr[ci * 16 + k];
                        #pragma unroll
                        for (int j = 0; j < 8; ++j)
                            acc[j] = fmaf(wk, xr[ci][16 + j - k], acc[j]);
                    }
                #pragma unroll
                for (int j = 0; j < 8; ++j)
                    res[j] = fmaf(o_head[j], acc[j], res[j]);
            }
            float* dst = out + (size_t)(b * 2 + cout) * NS + s0;
            float4 v0, v1;
            v0.x = res[0]; v0.y = res[1]; v0.z = res[2]; v0.w = res[3];
            v1.x = res[4]; v1.y = res[5]; v1.z = res[6]; v1.w = res[7];
            *(float4*)(dst)     = v0;
            *(float4*)(dst + 4) = v1;
        }
    }
}

extern "C" void kernel_launch(void* const* d_in, const int* in_sizes, int n_in,
                              void* d_out, int out_size, void* d_ws, size_t ws_size,
                              hipStream_t stream) {
    const float* x     = (const float*)d_in[0];
    const float* feats = (const float*)d_in[1];
    const float* ckw   = (const float*)d_in[2];
    const float* ckb   = (const float*)d_in[3];
    const float* fgw   = (const float*)d_in[4];
    const float* fgb   = (const float*)d_in[5];
    const float* owin  = (const float*)d_in[6];
    float* out  = (float*)d_out;
    float* wbuf = (float*)d_ws;                 // B*NF*64*4 = 4.1 MB

    hipLaunchKernelGGL(wcalc4_kernel, dim3(8, BB, 2), dim3(512), 0, stream,
                       feats, ckw, ckb, fgw, fgb, wbuf);

    hipLaunchKernelGGL(conv2_kernel, dim3((NBODY2 + NOV2) / 256), dim3(256), 0, stream,
                       x, wbuf, owin, out);
}

// Round 8
// 119.171 us; speedup vs baseline: 2.0809x; 1.0001x over previous
//
#include <hip/hip_runtime.h>

// Problem constants
#define BB    32
#define NF    500
#define FRAME 160
#define OV    40
#define KK    16
#define NS    (NF * FRAME)     // 80000
#define FEAT  256

#define NBODY2 (BB * NF * 15)   // 240000 threads: t in [40,160), both couts
#define NOV2   (BB * NF * 5)    //  80000 threads: t in [0,40),   both couts

// gain_a = (6+6)/2 * ln10/20 ; shape_gain = 10^(-6/20)
__device__ const float GAIN_A     = 0.6907755278982137f;
__device__ const float SHAPE_GAIN = 0.5011872336272722f;

// ---------------------------------------------------------------------------
// wcalc5: filter build, ALL operands in LDS (no global/scalar-mem in loop).
// Grid (8 f-tiles, 32 b, 2 cout), block 512 = 8 waves. Lane l = frame f0+l;
// wave w owns rows z*32 + w*4 .. +3.
//  - feats chunk staged as [fr][c4 ^ (fr&7)] float4-swizzled -> ds_read_b128
//    conflict-free (8 consecutive rows cover all 32 banks).
//  - this z's 32 ckw rows staged per 128-k chunk (16 KB); loop reads them at
//    wave-uniform addresses -> LDS broadcast, no conflicts, no s_loads.
//  - launch_bounds(512,4): VGPR cap 128 so loads can pipeline (R4's 28-VGPR
//    squeeze killed all ILP).
// ---------------------------------------------------------------------------
__global__ __launch_bounds__(512, 4) void wcalc5_kernel(
    const float* __restrict__ feats,  // (B, NF, 256)
    const float* __restrict__ ckw,    // (64, 256)
    const float* __restrict__ ckb,    // (64,)
    const float* __restrict__ fgw,    // (2, 256)
    const float* __restrict__ fgb,    // (2,)
    float* __restrict__ wout)         // (B*NF, 64)
{
    int tile = blockIdx.x;            // 0..7
    int b    = blockIdx.y;            // 0..31
    int z    = blockIdx.z;            // cout 0/1
    int f0   = tile * 64;
    int tid  = threadIdx.x;
    int w    = tid >> 6;              // 0..7
    int l    = tid & 63;              // frame offset

    __shared__ float sf[64 * 128];    // 32 KB feats chunk, swizzled
    __shared__ float wl[32 * 128];    // 16 KB ckw rows chunk
    __shared__ float gl[128];         // gain row chunk
    __shared__ float sr[8][64];       // ssq partials

    int w4 = w * 4;                   // local row base (0..28)
    float acc[4] = {0.f, 0.f, 0.f, 0.f};
    float g = 0.f;

    for (int h = 0; h < 2; ++h) {     // two 128-feat chunks
        __syncthreads();              // previous chunk's readers done
        #pragma unroll
        for (int p = 0; p < 4; ++p) {
            int F  = p * 512 + tid;   // 0..2047 float4 slots
            int fr = F >> 5;          // frame row 0..63
            int c4 = F & 31;          // float4 col
            int f  = f0 + fr;
            float4 v = make_float4(0.f, 0.f, 0.f, 0.f);
            if (f < NF)
                v = *(const float4*)(feats + ((size_t)(b * NF + f)) * FEAT
                                     + h * 128 + c4 * 4);
            *(float4*)(sf + fr * 128 + ((c4 ^ (fr & 7)) * 4)) = v;
        }
        #pragma unroll
        for (int p = 0; p < 2; ++p) {
            int S  = p * 512 + tid;   // 0..1023
            int r  = S >> 5;          // row 0..31
            int c4 = S & 31;
            float4 v = *(const float4*)(ckw + (size_t)(z * 32 + r) * FEAT
                                        + h * 128 + c4 * 4);
            *(float4*)(wl + r * 128 + c4 * 4) = v;
        }
        if (tid < 32) {
            float4 v = *(const float4*)(fgw + z * FEAT + h * 128 + tid * 4);
            *(float4*)(gl + tid * 4) = v;
        }
        __syncthreads();

        #pragma unroll 4
        for (int cl = 0; cl < 16; ++cl) {
            float4 fa = *(const float4*)(sf + l * 128 + (((2 * cl)     ^ (l & 7)) * 4));
            float4 fb = *(const float4*)(sf + l * 128 + (((2 * cl + 1) ^ (l & 7)) * 4));
            float fr8[8] = {fa.x, fa.y, fa.z, fa.w, fb.x, fb.y, fb.z, fb.w};
            #pragma unroll
            for (int r = 0; r < 4; ++r) {
                const float* wr = wl + (w4 + r) * 128 + cl * 8;
                float4 wa = *(const float4*)(wr);
                float4 wb = *(const float4*)(wr + 4);
                acc[r] = fmaf(fr8[0], wa.x, acc[r]);
                acc[r] = fmaf(fr8[1], wa.y, acc[r]);
                acc[r] = fmaf(fr8[2], wa.z, acc[r]);
                acc[r] = fmaf(fr8[3], wa.w, acc[r]);
                acc[r] = fmaf(fr8[4], wb.x, acc[r]);
                acc[r] = fmaf(fr8[5], wb.y, acc[r]);
                acc[r] = fmaf(fr8[6], wb.z, acc[r]);
                acc[r] = fmaf(fr8[7], wb.w, acc[r]);
            }
            const float* gr = gl + cl * 8;
            float4 ga = *(const float4*)(gr);
            float4 gb = *(const float4*)(gr + 4);
            g = fmaf(fr8[0], ga.x, g); g = fmaf(fr8[1], ga.y, g);
            g = fmaf(fr8[2], ga.z, g); g = fmaf(fr8[3], ga.w, g);
            g = fmaf(fr8[4], gb.x, g); g = fmaf(fr8[5], gb.y, g);
            g = fmaf(fr8[6], gb.z, g); g = fmaf(fr8[7], gb.w, g);
        }
    }

    int rbase = z * 32 + w4;          // global row base
    #pragma unroll
    for (int r = 0; r < 4; ++r) acc[r] += ckb[rbase + r];
    g += fgb[z];

    float ssq = 0.f;
    #pragma unroll
    for (int r = 0; r < 4; ++r) ssq = fmaf(acc[r], acc[r], ssq);
    sr[w][l] = ssq;
    __syncthreads();
    float tot = 0.f;
    #pragma unroll
    for (int j = 0; j < 8; ++j) tot += sr[j][l];
    float norm = 1e-6f + sqrtf(tot);

    float gain = expf(GAIN_A * tanhf(g));
    float sc   = gain * SHAPE_GAIN / norm;
    float idv  = gain * (1.0f - SHAPE_GAIN);

    int f = f0 + l;
    if (f < NF) {
        float o[4];
        #pragma unroll
        for (int r = 0; r < 4; ++r)
            o[r] = acc[r] * sc + ((((rbase + r) & 15) == 7) ? idv : 0.f);
        float4 v;
        v.x = o[0]; v.y = o[1]; v.z = o[2]; v.w = o[3];
        *(float4*)(wout + ((size_t)(b * NF + f)) * 64 + rbase) = v;
    }
}

// ---------------------------------------------------------------------------
// conv: direct conv + overlap-add. Each thread: 8 samples x BOTH couts
// (x window loaded once, couts sequential reusing wr/acc registers).
// Region split: [0, NBODY2) body t in [40,160); [NBODY2, +NOV2) overlap.
// UNCHANGED from round 5/7 for clean attribution of the wcalc change.
// ---------------------------------------------------------------------------
__global__ __launch_bounds__(256) void conv2_kernel(
    const float* __restrict__ x,     // (B, 2, NS)
    const float* __restrict__ w,     // (B*NF, 64)
    const float* __restrict__ owin,  // (40,)
    float* __restrict__ out)         // (B, 2, NS)
{
    int flat = blockIdx.x * 256 + threadIdx.x;   // 0 .. 319999
    if (flat < NBODY2) {
        int g    = flat % 15;
        int rest = flat / 15;
        int f    = rest % NF;
        int b    = rest / NF;
        int s0   = f * FRAME + OV + g * 8;       // >= 40: no underflow

        const float* xb = x + (size_t)b * 2 * NS;
        float xr[2][24];
        #pragma unroll
        for (int ci = 0; ci < 2; ++ci) {
            const float* xc = xb + (size_t)ci * NS + s0 - 16;
            #pragma unroll
            for (int c = 0; c < 6; ++c) {
                float4 v = *(const float4*)(xc + c * 4);
                xr[ci][c * 4 + 0] = v.x; xr[ci][c * 4 + 1] = v.y;
                xr[ci][c * 4 + 2] = v.z; xr[ci][c * 4 + 3] = v.w;
            }
        }
        const float* wfb = w + (size_t)(b * NF + f) * 64;
        #pragma unroll
        for (int cout = 0; cout < 2; ++cout) {
            const float4* wf = (const float4*)(wfb + cout * 32);
            float wr[32];
            #pragma unroll
            for (int q = 0; q < 8; ++q) {
                float4 v = wf[q];
                wr[q * 4 + 0] = v.x; wr[q * 4 + 1] = v.y;
                wr[q * 4 + 2] = v.z; wr[q * 4 + 3] = v.w;
            }
            float acc[8];
            #pragma unroll
            for (int j = 0; j < 8; ++j) acc[j] = 0.f;
            #pragma unroll
            for (int ci = 0; ci < 2; ++ci)
                #pragma unroll
                for (int k = 0; k < KK; ++k) {
                    float wk = wr[ci * 16 + k];
                    #pragma unroll
                    for (int j = 0; j < 8; ++j)
                        acc[j] = fmaf(wk, xr[ci][16 + j - k], acc[j]);
                }
            float* dst = out + (size_t)(b * 2 + cout) * NS + s0;
            float4 v0, v1;
            v0.x = acc[0]; v0.y = acc[1]; v0.z = acc[2]; v0.w = acc[3];
            v1.x = acc[4]; v1.y = acc[5]; v1.z = acc[6]; v1.w = acc[7];
            *(float4*)(dst)     = v0;
            *(float4*)(dst + 4) = v1;
        }
    } else {
        int flat2 = flat - NBODY2;
        int g    = flat2 % 5;
        int rest = flat2 / 5;
        int f    = rest % NF;
        int b    = rest / NF;
        int t0   = g * 8;
        int s0   = f * FRAME + t0;

        const float* xb = x + (size_t)b * 2 * NS;
        float xr[2][24];
        #pragma unroll
        for (int ci = 0; ci < 2; ++ci) {
            const float* xc = xb + (size_t)ci * NS + s0 - 16;
            #pragma unroll
            for (int c = 0; c < 6; ++c) {
                if (s0 - 16 + c * 4 >= 0) {
                    float4 v = *(const float4*)(xc + c * 4);
                    xr[ci][c * 4 + 0] = v.x; xr[ci][c * 4 + 1] = v.y;
                    xr[ci][c * 4 + 2] = v.z; xr[ci][c * 4 + 3] = v.w;
                } else {
                    xr[ci][c * 4 + 0] = 0.f; xr[ci][c * 4 + 1] = 0.f;
                    xr[ci][c * 4 + 2] = 0.f; xr[ci][c * 4 + 3] = 0.f;
                }
            }
        }

        // owin windows: o_tail[j] = owin[t0+j], o_head[j] = owin[39-t0-j]
        float o_tail[8], o_head[8];
        {
            float4 a = *(const float4*)(owin + t0);
            float4 c = *(const float4*)(owin + t0 + 4);
            o_tail[0] = a.x; o_tail[1] = a.y; o_tail[2] = a.z; o_tail[3] = a.w;
            o_tail[4] = c.x; o_tail[5] = c.y; o_tail[6] = c.z; o_tail[7] = c.w;
            float4 d = *(const float4*)(owin + (32 - t0));
            float4 e = *(const float4*)(owin + (36 - t0));
            o_head[0] = e.w; o_head[1] = e.z; o_head[2] = e.y; o_head[3] = e.x;
            o_head[4] = d.w; o_head[5] = d.z; o_head[6] = d.y; o_head[7] = d.x;
        }

        const float* wfb = w + (size_t)(b * NF + f) * 64;
        #pragma unroll
        for (int cout = 0; cout < 2; ++cout) {
            float res[8];
            #pragma unroll
            for (int j = 0; j < 8; ++j) res[j] = 0.f;

            float wr[32];
            if (f > 0) {   // previous frame's filter (tail contribution)
                const float4* wp = (const float4*)(wfb - 64 + cout * 32);
                #pragma unroll
                for (int q = 0; q < 8; ++q) {
                    float4 v = wp[q];
                    wr[q * 4 + 0] = v.x; wr[q * 4 + 1] = v.y;
                    wr[q * 4 + 2] = v.z; wr[q * 4 + 3] = v.w;
                }
                float acc[8];
                #pragma unroll
                for (int j = 0; j < 8; ++j) acc[j] = 0.f;
                #pragma unroll
                for (int ci = 0; ci < 2; ++ci)
                    #pragma unroll
                    for (int k = 0; k < KK; ++k) {
                        float wk = wr[ci * 16 + k];
                        #pragma unroll
                        for (int j = 0; j < 8; ++j)
                            acc[j] = fmaf(wk, xr[ci][16 + j - k], acc[j]);
                    }
                #pragma unroll
                for (int j = 0; j < 8; ++j) res[j] = o_tail[j] * acc[j];
            }
            {
                const float4* wf = (const float4*)(wfb + cout * 32);
                #pragma unroll
                for (int q = 0; q < 8; ++q) {
                    float4 v = wf[q];
                    wr[q * 4 + 0] = v.x; wr[q * 4 + 1] = v.y;
                    wr[q * 4 + 2] = v.z; wr[q * 4 + 3] = v.w;
                }
                float acc[8];
                #pragma unroll
                for (int j = 0; j < 8; ++j) acc[j] = 0.f;
                #pragma unroll
                for (int ci = 0; ci < 2; ++ci)
                    #pragma unroll
                    for (int k = 0; k < KK; ++k) {
                        float wk = wr[ci * 16 + k];
                        #pragma unroll
                        for (int j = 0; j < 8; ++j)
                            acc[j] = fmaf(wk, xr[ci][16 + j - k], acc[j]);
                    }
                #pragma unroll
                for (int j = 0; j < 8; ++j)
                    res[j] = fmaf(o_head[j], acc[j], res[j]);
            }
            float* dst = out + (size_t)(b * 2 + cout) * NS + s0;
            float4 v0, v1;
            v0.x = res[0]; v0.y = res[1]; v0.z = res[2]; v0.w = res[3];
            v1.x = res[4]; v1.y = res[5]; v1.z = res[6]; v1.w = res[7];
            *(float4*)(dst)     = v0;
            *(float4*)(dst + 4) = v1;
        }
    }
}

extern "C" void kernel_launch(void* const* d_in, const int* in_sizes, int n_in,
                              void* d_out, int out_size, void* d_ws, size_t ws_size,
                              hipStream_t stream) {
    const float* x     = (const float*)d_in[0];
    const float* feats = (const float*)d_in[1];
    const float* ckw   = (const float*)d_in[2];
    const float* ckb   = (const float*)d_in[3];
    const float* fgw   = (const float*)d_in[4];
    const float* fgb   = (const float*)d_in[5];
    const float* owin  = (const float*)d_in[6];
    float* out  = (float*)d_out;
    float* wbuf = (float*)d_ws;                 // B*NF*64*4 = 4.1 MB

    hipLaunchKernelGGL(wcalc5_kernel, dim3(8, BB, 2), dim3(512), 0, stream,
                       feats, ckw, ckb, fgw, fgb, wbuf);

    hipLaunchKernelGGL(conv2_kernel, dim3((NBODY2 + NOV2) / 256), dim3(256), 0, stream,
                       x, wbuf, owin, out);
}